// Round 1
// baseline (455.227 us; speedup 1.0000x reference)
//
#include <hip/hip_runtime.h>

#define B 64
#define K 8
#define V 128000
#define CH 4096
#define NCH 32   // ceil(V/CH) = 31.25 -> 32 (chunk 31 holds 1024 elems)

// ---------------------------------------------------------------------------
// Kernel 1: per-batch accept chain. 8 scattered gathers per batch.
// meta[b] = num_accepted; also writes num_accepted output (d_out + 576).
// ---------------------------------------------------------------------------
__global__ __launch_bounds__(64) void k1_accept(
    const int*   __restrict__ draft_tokens,
    const float* __restrict__ draft_probs,
    const float* __restrict__ oracle_probs,
    const float* __restrict__ uniforms,
    int* __restrict__ meta,
    int* __restrict__ out_na)
{
  int b = threadIdx.x;
  if (b >= B) return;
  int na = 0;
  for (int k = 0; k < K; ++k) {
    int t   = draft_tokens[b * K + k];
    float pd = draft_probs [((size_t)(b * K       + k)) * V + t];
    float po = oracle_probs[((size_t)(b * (K + 1) + k)) * V + t];
    float ap = fminf(1.0f, po / pd);
    if (uniforms[b * K + k] < ap) na++; else break;
  }
  meta[b]   = na;
  out_na[b] = na;
}

// ---------------------------------------------------------------------------
// Kernel 2: per (batch, chunk) partial sums of final_dist.
//   all_accepted: dist = oracle[b, K, :]          (bonus row)
//   otherwise:    dist = max(oracle[b,r]-draft[b,r], 0)  (unnormalized)
// grid = B*NCH blocks of 256 threads; each block sums CH=4096 elems (float4).
// ---------------------------------------------------------------------------
__global__ __launch_bounds__(256) void k2_sums(
    const float* __restrict__ draft_probs,
    const float* __restrict__ oracle_probs,
    const int*   __restrict__ meta,
    float* __restrict__ chunkSums)
{
  const int b = blockIdx.x >> 5;
  const int c = blockIdx.x & 31;
  const int na  = meta[b];
  const bool acc = (na == K);
  const int row = acc ? K : na;             // min(na, K-1) == na when na < K
  const float* orow = oracle_probs + ((size_t)(b * (K + 1) + row)) * V;
  const float* drow = draft_probs  + ((size_t)(b * K       + row)) * V;

  const int base = c * CH;
  float s = 0.f;
#pragma unroll
  for (int it = 0; it < 4; ++it) {
    int idx = base + it * 1024 + (int)threadIdx.x * 4;
    if (idx < V) {
      float4 o = *(const float4*)(orow + idx);
      if (acc) {
        s += (o.x + o.y) + (o.z + o.w);
      } else {
        float4 d = *(const float4*)(drow + idx);
        s += fmaxf(o.x - d.x, 0.f) + fmaxf(o.y - d.y, 0.f)
           + fmaxf(o.z - d.z, 0.f) + fmaxf(o.w - d.w, 0.f);
      }
    }
  }
  // wave reduce (wave = 64)
  for (int off = 32; off > 0; off >>= 1) s += __shfl_down(s, off);
  __shared__ float wsum[4];
  int lane = threadIdx.x & 63, w = threadIdx.x >> 6;
  if (lane == 0) wsum[w] = s;
  __syncthreads();
  if (threadIdx.x == 0)
    chunkSums[b * NCH + c] = (wsum[0] + wsum[1]) + (wsum[2] + wsum[3]);
}

// ---------------------------------------------------------------------------
// Kernel 3: one block per batch. Scan 32 chunk sums -> crossing chunk ->
// re-read only that 16 KB chunk -> exact index. Writes the 9-token row.
// ---------------------------------------------------------------------------
__global__ __launch_bounds__(256) void k3_sample(
    const int*   __restrict__ draft_tokens,
    const float* __restrict__ draft_probs,
    const float* __restrict__ oracle_probs,
    const float* __restrict__ sample_u,
    const int*   __restrict__ meta,
    const float* __restrict__ chunkSums,
    int* __restrict__ out_tokens)
{
  const int b    = blockIdx.x;
  const int tid  = threadIdx.x;
  const int lane = tid & 63, w = tid >> 6;

  const int na   = meta[b];
  const bool acc = (na == K);
  const int row  = acc ? K : na;
  const float* orow = oracle_probs + ((size_t)(b * (K + 1) + row)) * V;
  const float* drow = draft_probs  + ((size_t)(b * K       + row)) * V;

  __shared__ float sT, sBase;
  __shared__ int   sC, sIdx;
  __shared__ float sWS[4];

  if (w == 0) {
    float v = (lane < NCH) ? chunkSums[b * NCH + lane] : 0.f;
    float incl = v;
    for (int off = 1; off < NCH; off <<= 1) {
      float n = __shfl_up(incl, off);
      if (lane >= off) incl += n;
    }
    float S = __shfl(incl, NCH - 1);
    float T = acc ? sample_u[b] : sample_u[b] * S;   // unnormalized threshold
    unsigned long long m = __ballot(lane < NCH && incl >= T);
    if (lane == 0) {
      sT = T;
      if (m == 0ULL) { sC = -1; sIdx = V - 1; sBase = 0.f; }
    }
    if (m != 0ULL) {
      int cstar = __ffsll((long long)m) - 1;
      if (lane == cstar) {
        sC = cstar;
        sBase = incl - v;                       // exclusive prefix
        int fb = cstar * CH + CH - 1;           // fallback: end of chunk
        sIdx = fb < V ? fb : V - 1;
      }
    }
  }
  __syncthreads();

  const int cstar = sC;     // uniform across block
  int new_token;
  if (cstar >= 0) {
    const float T = sT;
    const int base = cstar * CH;
    const int estart = base + tid * 16;        // 16 contiguous elems / thread
    float vals[16];
    float s = 0.f;
#pragma unroll
    for (int j4 = 0; j4 < 4; ++j4) {
      int idx = estart + j4 * 4;
      float4 o = make_float4(0.f, 0.f, 0.f, 0.f);
      float4 d = make_float4(0.f, 0.f, 0.f, 0.f);
      if (idx < V) {
        o = *(const float4*)(orow + idx);
        if (!acc) d = *(const float4*)(drow + idx);
      }
      float v0 = acc ? o.x : fmaxf(o.x - d.x, 0.f);
      float v1 = acc ? o.y : fmaxf(o.y - d.y, 0.f);
      float v2 = acc ? o.z : fmaxf(o.z - d.z, 0.f);
      float v3 = acc ? o.w : fmaxf(o.w - d.w, 0.f);
      vals[j4 * 4 + 0] = v0; vals[j4 * 4 + 1] = v1;
      vals[j4 * 4 + 2] = v2; vals[j4 * 4 + 3] = v3;
      s += (v0 + v1) + (v2 + v3);
    }
    // block-wide exclusive prefix of per-thread sums
    float incl = s;
    for (int off = 1; off < 64; off <<= 1) {
      float n = __shfl_up(incl, off);
      if (lane >= off) incl += n;
    }
    if (lane == 63) sWS[w] = incl;
    __syncthreads();
    float woff = 0.f;
    for (int i = 0; i < w; ++i) woff += sWS[i];
    float run = sBase + woff + (incl - s);
    int found = -1;
#pragma unroll
    for (int j = 0; j < 16; ++j) {
      run += vals[j];
      if (found < 0 && run >= T) found = estart + j;
    }
    if (found >= 0 && found < V) atomicMin(&sIdx, found);
    __syncthreads();
    new_token = sIdx;
  } else {
    new_token = V - 1;
  }

  // token row: pos<na -> draft, pos==na -> new_token, else -1
  if (tid < K + 1) {
    int pos = tid, val;
    if (pos < na)       val = draft_tokens[b * K + pos];  // pos<na implies pos<K
    else if (pos == na) val = new_token;
    else                val = -1;
    out_tokens[b * (K + 1) + pos] = val;
  }
}

// ---------------------------------------------------------------------------
extern "C" void kernel_launch(void* const* d_in, const int* in_sizes, int n_in,
                              void* d_out, int out_size, void* d_ws, size_t ws_size,
                              hipStream_t stream) {
  const int*   draft_tokens = (const int*)  d_in[0];
  const float* draft_probs  = (const float*)d_in[1];
  /* d_in[2] = oracle_tokens (unused by the reference math) */
  const float* oracle_probs = (const float*)d_in[3];
  const float* uniforms     = (const float*)d_in[4];
  const float* sample_u     = (const float*)d_in[5];
  /* d_in[6] = num_draft_tokens == K (hardcoded) */

  int* out_tokens = (int*)d_out;                 // [B, K+1] = 576
  int* out_na     = out_tokens + B * (K + 1);    // [B]      = 64

  float* chunkSums = (float*)d_ws;               // B*NCH floats = 8 KB
  int*   meta      = (int*)d_ws + B * NCH;       // B ints

  k1_accept<<<1, 64, 0, stream>>>(draft_tokens, draft_probs, oracle_probs,
                                  uniforms, meta, out_na);
  k2_sums<<<B * NCH, 256, 0, stream>>>(draft_probs, oracle_probs, meta, chunkSums);
  k3_sample<<<B, 256, 0, stream>>>(draft_tokens, draft_probs, oracle_probs,
                                   sample_u, meta, chunkSums, out_tokens);
}